// Round 4
// baseline (430.266 us; speedup 1.0000x reference)
//
#include <hip/hip_runtime.h>

// Problem constants (from reference): B=2048, N=1024, C=128, M=64
constexpr int kB  = 2048;
constexpr int kN  = 1024;
constexpr int kC  = 128;
constexpr int kM  = 64;
constexpr int kC4 = kC / 4;    // float4 chunks per row = 32

constexpr int RPB   = 64;            // rows per block
constexpr int BPB   = kN / RPB;      // row-blocks per batch = 16
constexpr int ITEMS = RPB * kC4 / 256;  // float4 items per thread = 8

using f4 = __attribute__((ext_vector_type(4))) float;

// ---------------------------------------------------------------------------
// Fused erase-add gate — barrier-free, LDS-free.
// One block = 64 rows of one batch; each wave is fully independent:
//  - lane m holds indices[b][m] in a register (kM == wave width == 64);
//  - __ballot marks which index slots fall in this block's row range;
//  - hot path: 8 unrolled nontemporal float4 loads -> stores (touch-once
//    streams skip L2 allocate; no __syncthreads -> compiler emits counted
//    vmcnt so stores overlap outstanding loads);
//  - rare path (~6% of rows): walk the ballot mask (avg ~4 bits), broadcast
//    idx[m] via uniform-lane __shfl (scalar readlane), accumulate matching
//    tar rows in index order (duplicates sum; erase zeroes the src term).
// Every output element is written exactly once per call (deterministic).
// ---------------------------------------------------------------------------
__global__ __launch_bounds__(256) void eag_fused(const f4* __restrict__ src,
                                                 const f4* __restrict__ tar,
                                                 const int* __restrict__ indices,
                                                 f4* __restrict__ out) {
    const int bid  = blockIdx.x;
    const int b    = bid >> 4;                 // / BPB
    const int row0 = (bid & (BPB - 1)) * RPB;
    const int tid  = threadIdx.x;
    const int lane = tid & 63;

    // Kick off the bulk stream first: 8 independent 16B loads in flight.
    const long long base = ((long long)b * kN + row0) * kC4;
    f4 v[ITEMS];
#pragma unroll
    for (int k = 0; k < ITEMS; ++k) {
        v[k] = __builtin_nontemporal_load(src + base + tid + k * 256);
    }

    // Per-wave index bookkeeping, register-resident (overlaps the loads).
    const int my_idx = indices[b * kM + lane];
    const int rel    = my_idx - row0;
    const unsigned long long mask = __ballot(rel >= 0 && rel < RPB);

    // Rare path: rows hit by an index get the accumulated tar sum instead.
    const f4* tb = tar + (long long)b * kM * kC4;
    const int c4 = tid & (kC4 - 1);
#pragma unroll
    for (int k = 0; k < ITEMS; ++k) {
        const int n = row0 + ((tid + k * 256) >> 5);   // this item's row
        f4 acc = {0.f, 0.f, 0.f, 0.f};
        bool hit = false;
        for (unsigned long long mm = mask; mm; mm &= mm - 1) {
            const int m = (int)__builtin_ctzll(mm);    // uniform (SGPR) lane id
            const int t = __shfl(my_idx, m);           // broadcast: readlane
            if (t == n) {
                hit = true;
                acc += tb[m * kC4 + c4];
            }
        }
        if (hit) v[k] = acc;
    }

    // Stores: nontemporal, coalesced; overlap remaining loads via counted vmcnt.
#pragma unroll
    for (int k = 0; k < ITEMS; ++k) {
        __builtin_nontemporal_store(v[k], out + base + tid + k * 256);
    }
}

extern "C" void kernel_launch(void* const* d_in, const int* in_sizes, int n_in,
                              void* d_out, int out_size, void* d_ws, size_t ws_size,
                              hipStream_t stream) {
    const f4*  src     = (const f4*)d_in[0];
    const f4*  tar     = (const f4*)d_in[1];
    const int* indices = (const int*)d_in[2];
    f4*        out     = (f4*)d_out;

    eag_fused<<<kB * BPB, 256, 0, stream>>>(src, tar, indices, out);
}